// Round 3
// baseline (1098.202 us; speedup 1.0000x reference)
//
#include <hip/hip_runtime.h>
#include <cstddef>
#include <cstring>

#define B_    2
#define L_    2048
#define DM_   1024
#define NH_   16
#define DH_   64
#define SCALE_ 0.125f   // 1/sqrt(64)

typedef __bf16 bf16x8 __attribute__((ext_vector_type(8)));
typedef float  f32x4  __attribute__((ext_vector_type(4)));
typedef unsigned short ushort8v __attribute__((ext_vector_type(8)));
typedef unsigned long long u64;
typedef unsigned int u32;

__device__ __forceinline__ u32 flipf(float f) {
    u32 u = __float_as_uint(f);
    return (u & 0x80000000u) ? ~u : (u | 0x80000000u);
}
__device__ __forceinline__ float unflipf(u32 k) {
    u32 u = (k & 0x80000000u) ? (k ^ 0x80000000u) : ~k;
    return __uint_as_float(u);
}
__device__ __forceinline__ float bf2f(unsigned short u) {
    return __uint_as_float(((u32)u) << 16);
}
__device__ __forceinline__ unsigned short f2bf(float f) {
    __bf16 h = (__bf16)f;
    unsigned short u;
    __builtin_memcpy(&u, &h, 2);
    return u;
}
// ascending bitonic sort of one u64 per lane across 64 lanes
__device__ __forceinline__ u64 bsort64_asc(u64 v, int lane) {
    #pragma unroll
    for (int k = 2; k <= 64; k <<= 1) {
        #pragma unroll
        for (int j = k >> 1; j >= 1; j >>= 1) {
            u64 ov = __shfl_xor(v, j);
            bool keepMin = (((lane & k) == 0) == ((lane & j) == 0));
            bool less = v < ov;
            v = (keepMin == less) ? v : ov;
        }
    }
    return v;
}

// ---------------------------------------------------------------------------
// GEMM 128x128 tile, 8x8 microtile, fp32, C = A(MxK) @ W(KxN)
// ---------------------------------------------------------------------------
__global__ __launch_bounds__(256)
void gemm128(const float* __restrict__ A, const float* __restrict__ W,
             float* __restrict__ C, int N, int K) {
    __shared__ float As[16][136];
    __shared__ float Ws[16][136];
    const int t  = threadIdx.x;
    const int bm = blockIdx.y << 7;
    const int bn = blockIdx.x << 7;
    const int tm = (t >> 4) << 3;
    const int tn = (t & 15) << 3;
    float acc[8][8] = {};
    const int am = t >> 1;
    const int ak = (t & 1) << 3;
    const int wk = t >> 4;
    const int wn = (t & 15) << 3;
    const float* Ap = A + (size_t)(bm + am) * K + ak;
    const float* Wp = W + (size_t)wk * N + bn + wn;
    for (int k0 = 0; k0 < K; k0 += 16) {
        float4 a0 = *(const float4*)(Ap + k0);
        float4 a1 = *(const float4*)(Ap + k0 + 4);
        float4 w0 = *(const float4*)(Wp + (size_t)k0 * N);
        float4 w1 = *(const float4*)(Wp + (size_t)k0 * N + 4);
        __syncthreads();
        As[ak+0][am] = a0.x; As[ak+1][am] = a0.y; As[ak+2][am] = a0.z; As[ak+3][am] = a0.w;
        As[ak+4][am] = a1.x; As[ak+5][am] = a1.y; As[ak+6][am] = a1.z; As[ak+7][am] = a1.w;
        *(float4*)&Ws[wk][wn]     = w0;
        *(float4*)&Ws[wk][wn + 4] = w1;
        __syncthreads();
        #pragma unroll
        for (int kk = 0; kk < 16; ++kk) {
            float a_[8], w_[8];
            *(float4*)&a_[0] = *(const float4*)&As[kk][tm];
            *(float4*)&a_[4] = *(const float4*)&As[kk][tm + 4];
            *(float4*)&w_[0] = *(const float4*)&Ws[kk][tn];
            *(float4*)&w_[4] = *(const float4*)&Ws[kk][tn + 4];
            #pragma unroll
            for (int i = 0; i < 8; ++i)
                #pragma unroll
                for (int j = 0; j < 8; ++j)
                    acc[i][j] += a_[i] * w_[j];
        }
    }
    #pragma unroll
    for (int i = 0; i < 8; ++i) {
        float* Cp = C + (size_t)(bm + tm + i) * N + bn + tn;
        float4 o0 = {acc[i][0], acc[i][1], acc[i][2], acc[i][3]};
        float4 o1 = {acc[i][4], acc[i][5], acc[i][6], acc[i][7]};
        *(float4*)Cp       = o0;
        *(float4*)(Cp + 4) = o1;
    }
}

// ---------------------------------------------------------------------------
// GEMM 64x64 tile, 4x4 microtile (skinny kv projection, N=128)
// ---------------------------------------------------------------------------
__global__ __launch_bounds__(256)
void gemm64(const float* __restrict__ A, const float* __restrict__ W,
            float* __restrict__ C, int N, int K) {
    __shared__ float As[16][68];
    __shared__ float Ws[16][68];
    const int t  = threadIdx.x;
    const int bm = blockIdx.y << 6;
    const int bn = blockIdx.x << 6;
    const int tm = (t >> 4) << 2;
    const int tn = (t & 15) << 2;
    float acc[4][4] = {};
    const int am = t >> 2;
    const int ak = (t & 3) << 2;
    const int wk = t >> 4;
    const int wn = (t & 15) << 2;
    const float* Ap = A + (size_t)(bm + am) * K + ak;
    const float* Wp = W + (size_t)wk * N + bn + wn;
    for (int k0 = 0; k0 < K; k0 += 16) {
        float4 av = *(const float4*)(Ap + k0);
        float4 wv = *(const float4*)(Wp + (size_t)k0 * N);
        __syncthreads();
        As[ak+0][am] = av.x; As[ak+1][am] = av.y; As[ak+2][am] = av.z; As[ak+3][am] = av.w;
        *(float4*)&Ws[wk][wn] = wv;
        __syncthreads();
        #pragma unroll
        for (int kk = 0; kk < 16; ++kk) {
            float a_[4], w_[4];
            *(float4*)&a_[0] = *(const float4*)&As[kk][tm];
            *(float4*)&w_[0] = *(const float4*)&Ws[kk][tn];
            #pragma unroll
            for (int i = 0; i < 4; ++i)
                #pragma unroll
                for (int j = 0; j < 4; ++j)
                    acc[i][j] += a_[i] * w_[j];
        }
    }
    #pragma unroll
    for (int i = 0; i < 4; ++i) {
        float4 o = {acc[i][0], acc[i][1], acc[i][2], acc[i][3]};
        *(float4*)(C + (size_t)(bm + tm + i) * N + bn + tn) = o;
    }
}

// ---------------------------------------------------------------------------
// Column (sequence-axis) L2 norms of kv -> inv_norm[b][c]
// ---------------------------------------------------------------------------
__global__ __launch_bounds__(256)
void col_norms(const float* __restrict__ kv, float* __restrict__ invn) {
    const int bc = blockIdx.x;
    const int b  = bc >> 7;
    const int c  = bc & 127;
    const int t  = threadIdx.x;
    const float* base = kv + (size_t)b * L_ * 128 + c;
    float ss = 0.f;
    for (int l = t; l < L_; l += 256) {
        float x = base[(size_t)l * 128];
        ss += x * x;
    }
    #pragma unroll
    for (int off = 32; off; off >>= 1) ss += __shfl_xor(ss, off);
    __shared__ float red[4];
    if ((t & 63) == 0) red[t >> 6] = ss;
    __syncthreads();
    if (t == 0) {
        float tot = red[0] + red[1] + red[2] + red[3];
        invn[bc] = 1.f / fmaxf(sqrtf(tot), 1e-12f);
    }
}

// ---------------------------------------------------------------------------
// Scale kv by inv-norms: kn fp32 (b,l,64), kh bf16 (b,l,64), vT bf16 (b,64,l)
// ---------------------------------------------------------------------------
__global__ __launch_bounds__(256)
void scale_kv(const float* __restrict__ kv, const float* __restrict__ invn,
              float* __restrict__ kn, __bf16* __restrict__ kh,
              __bf16* __restrict__ vT) {
    const int b  = blockIdx.y;
    const int l0 = blockIdx.x << 6;
    const int t  = threadIdx.x;
    __shared__ float s_inv[128];
    __shared__ float s_vt[64][65];
    if (t < 128) s_inv[t] = invn[b * 128 + t];
    __syncthreads();
    #pragma unroll
    for (int rep = 0; rep < 8; ++rep) {
        int idx = (rep << 8) + t;          // 0..2047
        int li  = idx >> 5;                // 0..63
        int c4  = (idx & 31) << 2;         // 0..124
        float4 x = *(const float4*)(kv + ((size_t)(b * L_ + l0 + li)) * 128 + c4);
        x.x *= s_inv[c4]; x.y *= s_inv[c4+1]; x.z *= s_inv[c4+2]; x.w *= s_inv[c4+3];
        if (c4 < 64) {
            size_t o = ((size_t)(b * L_ + l0 + li)) * DH_ + c4;
            *(float4*)(kn + o) = x;
            kh[o+0] = (__bf16)x.x; kh[o+1] = (__bf16)x.y;
            kh[o+2] = (__bf16)x.z; kh[o+3] = (__bf16)x.w;
        } else {
            int d = c4 - 64;
            s_vt[d+0][li] = x.x; s_vt[d+1][li] = x.y; s_vt[d+2][li] = x.z; s_vt[d+3][li] = x.w;
        }
    }
    __syncthreads();
    #pragma unroll
    for (int rep = 0; rep < 4; ++rep) {
        int idx = (rep << 8) + t;          // 0..1023
        int d   = idx >> 4;                // 0..63
        int j   = (idx & 15) << 2;         // 0..60
        size_t o = ((size_t)b * DH_ + d) * L_ + l0 + j;
        vT[o+0] = (__bf16)s_vt[d][j+0];
        vT[o+1] = (__bf16)s_vt[d][j+1];
        vT[o+2] = (__bf16)s_vt[d][j+2];
        vT[o+3] = (__bf16)s_vt[d][j+3];
    }
}

// ---------------------------------------------------------------------------
// Fused: single-bf16 MFMA sims -> bf16 LDS; top-32 (threshold+margin, exact
// fp32 refine, bitonic); exp in place; bf16 MFMA local with ds_add reduction;
// exact retrieved. Block: 1024 thr (16 waves) = (b, h, 16 q-rows).
// LDS 78.3 KB -> 2 blocks/CU; __launch_bounds__(1024,8) caps VGPR at 64.
// ---------------------------------------------------------------------------
__global__ __launch_bounds__(1024, 8)
void attn_topk(const float* __restrict__ q,    // (B, L, 1024) fp32
               const float* __restrict__ kn,   // (B, L, 64)  fp32
               const __bf16* __restrict__ kh,  // (B, L, 64)  bf16
               const __bf16* __restrict__ vT,  // (B, 64, L)  bf16
               float* __restrict__ attn) {     // (B, L, 1024)
    const int l0   = blockIdx.x << 4;
    const int h    = blockIdx.y;
    const int b    = blockIdx.z;
    const int t    = threadIdx.x;
    const int w    = t >> 6;          // wave 0..15
    const int lane = t & 63;
    const int quad = lane >> 4;
    const int n15  = lane & 15;

    __shared__ unsigned short s_sims[16][2056];   // 65,792 B (bf16 sims -> p)
    __shared__ float          s_qrow[16][64];     //  4,096 B (fp32 q for refine)
    __shared__ unsigned short s_cand[16][128];    //  4,096 B (candidate indices)
    __shared__ float          s_rowmax[16];
    __shared__ float          s_denom[16];
    __shared__ float          s_local[16][66];    //  4,224 B
    // total 78,336 B -> 2 blocks/CU

    // ---- init: zero accumulators, stage fp32 q rows ----
    {
        float* sl = &s_local[0][0];
        for (int i = t; i < 16 * 66; i += 1024) sl[i] = 0.f;
        if (t < 16) s_denom[t] = 0.f;
        s_qrow[w][lane] = q[((size_t)(b * L_ + l0 + w)) * DM_ + h * DH_ + lane];
    }

    // ---- phase S: sims via single bf16 MFMA (wave w -> m in [128w,128w+128)) ----
    {
        bf16x8 qf[2];
        const float* qp = q + ((size_t)(b * L_ + l0 + n15)) * DM_ + h * DH_ + (quad << 3);
        #pragma unroll
        for (int ks = 0; ks < 2; ++ks) {
            float4 x0 = *(const float4*)(qp + (ks << 5));
            float4 x1 = *(const float4*)(qp + (ks << 5) + 4);
            float xv[8] = {x0.x, x0.y, x0.z, x0.w, x1.x, x1.y, x1.z, x1.w};
            #pragma unroll
            for (int i2 = 0; i2 < 8; ++i2) qf[ks][i2] = (__bf16)xv[i2];
        }
        const __bf16* khb = kh + (size_t)b * L_ * DH_;
        #pragma unroll 2
        for (int j = 0; j < 8; ++j) {
            int m0 = (w << 7) + (j << 4);
            const __bf16* kp = khb + (size_t)(m0 + n15) * DH_ + (quad << 3);
            bf16x8 k0 = *(const bf16x8*)(kp);
            bf16x8 k1 = *(const bf16x8*)(kp + 32);
            f32x4 acc = {0.f, 0.f, 0.f, 0.f};
            acc = __builtin_amdgcn_mfma_f32_16x16x32_bf16(qf[0], k0, acc, 0, 0, 0);
            acc = __builtin_amdgcn_mfma_f32_16x16x32_bf16(qf[1], k1, acc, 0, 0, 0);
            #pragma unroll
            for (int rr = 0; rr < 4; ++rr)
                s_sims[(quad << 2) + rr][m0 + n15] = f2bf(acc[rr]);
        }
    }
    __syncthreads();   // #1: sims + qrow + zeros visible

    // ---- phase T: per-row threshold scan + candidate compaction (wave w = row w) ----
    int C;
    {
        const int r = w;
        const unsigned short* srow = &s_sims[r][0];
        float bv = -3e38f;
        #pragma unroll
        for (int j = 0; j < 4; ++j) {
            ushort8v uv = *(const ushort8v*)(srow + (j << 9) + (lane << 3));
            #pragma unroll
            for (int e = 0; e < 8; ++e) bv = fmaxf(bv, bf2f(uv[e]));
        }
        // sort the 64 lane-maxima descending (ascending on ~flipped keys)
        unsigned mk = ~flipf(bv);
        #pragma unroll
        for (int k = 2; k <= 64; k <<= 1) {
            #pragma unroll
            for (int j = k >> 1; j >= 1; j >>= 1) {
                unsigned ov = __shfl_xor(mk, j);
                bool keepMin = (((lane & k) == 0) == ((lane & j) == 0));
                bool less = mk < ov;
                mk = (keepMin == less) ? mk : ov;
            }
        }
        float smaxf = unflipf(~__shfl(mk, 0));            // row max of approx sims
        float thrf  = unflipf(~__shfl(mk, 31)) - 0.01f;   // m_(32) minus 2eps margin
        if (lane == 0) s_rowmax[r] = smaxf;
        // count candidates >= threshold
        int c = 0;
        #pragma unroll
        for (int j = 0; j < 4; ++j) {
            ushort8v uv = *(const ushort8v*)(srow + (j << 9) + (lane << 3));
            #pragma unroll
            for (int e = 0; e < 8; ++e) c += (bf2f(uv[e]) >= thrf) ? 1 : 0;
        }
        int incl = c;
        #pragma unroll
        for (int off = 1; off < 64; off <<= 1) {
            int ns = __shfl_up(incl, off);
            if (lane >= off) incl += ns;
        }
        C = __shfl(incl, 63);
        int o = incl - c;
        #pragma unroll 1
        for (int j = 0; j < 4; ++j) {
            ushort8v uv = *(const ushort8v*)(srow + (j << 9) + (lane << 3));
            #pragma unroll
            for (int e = 0; e < 8; ++e) {
                if (bf2f(uv[e]) >= thrf) {
                    if (o < 128) s_cand[r][o] = (unsigned short)((j << 9) + (lane << 3) + e);
                    ++o;
                }
            }
        }
        if (C > 128) C = 128;   // statistically unreachable (C typ ~50)
    }
    __syncthreads();   // #2: rowmax + cand visible; sims may now be overwritten

    // ---- phase L0: p = exp(scale*(s-max)) in place (own m-slice, all 16 rows) ----
    {
        const int rowL = lane >> 2;
        const int sub  = lane & 3;
        float mr = s_rowmax[rowL];
        float dsum = 0.f;
        unsigned short* sp = &s_sims[rowL][(w << 7) + (sub << 5)];
        #pragma unroll
        for (int j = 0; j < 4; ++j) {
            ushort8v uv = *(const ushort8v*)(sp + (j << 3));
            ushort8v pv;
            #pragma unroll
            for (int e = 0; e < 8; ++e) {
                float p = __expf(SCALE_ * (bf2f(uv[e]) - mr));
                dsum += p;
                pv[e] = f2bf(p);
            }
            *(ushort8v*)(sp + (j << 3)) = pv;
        }
        dsum += __shfl_xor(dsum, 1);
        dsum += __shfl_xor(dsum, 2);
        if (sub == 0) atomicAdd(&s_denom[rowL], dsum);
    }

    // ---- phase L1: local += p @ v (own slice; bf16 MFMA; ds_add reduction) ----
    {
        f32x4 accL[4] = {{0,0,0,0},{0,0,0,0},{0,0,0,0},{0,0,0,0}};
        const __bf16* vtb = vT + (size_t)b * DH_ * L_;
        #pragma unroll
        for (int ks = 0; ks < 4; ++ks) {
            int mb = (w << 7) + (ks << 5);
            ushort8v pu = *(const ushort8v*)&s_sims[n15][mb + (quad << 3)];
            bf16x8 af;
            __builtin_memcpy(&af, &pu, 16);
            #pragma unroll
            for (int nn = 0; nn < 4; ++nn) {
                bf16x8 bv8 = *(const bf16x8*)(vtb + (size_t)((nn << 4) + n15) * L_ + mb + (quad << 3));
                accL[nn] = __builtin_amdgcn_mfma_f32_16x16x32_bf16(af, bv8, accL[nn], 0, 0, 0);
            }
        }
        #pragma unroll
        for (int nn = 0; nn < 4; ++nn)
            #pragma unroll
            for (int rr = 0; rr < 4; ++rr)
                atomicAdd(&s_local[(quad << 2) + rr][(nn << 4) + n15], accL[nn][rr]);
    }

    // ---- phase F: exact fp32 refine of candidates + bitonic top-32 ----
    int   myci = 0;
    float mycv = -3e38f;
    {
        const int r = w;
        const float* knb = kn + (size_t)b * L_ * DH_;
        u64 keyA, keyB = 0;
        {
            bool act = lane < C;
            int m = act ? (int)s_cand[r][lane] : 0;
            const float* kr = knb + (size_t)m * DH_;
            float dot = 0.f;
            #pragma unroll
            for (int d4 = 0; d4 < 16; ++d4) {
                float4 kx = *(const float4*)(kr + (d4 << 2));
                float4 qx = *(const float4*)&s_qrow[r][d4 << 2];
                dot += kx.x * qx.x + kx.y * qx.y + kx.z * qx.z + kx.w * qx.w;
            }
            keyA = act ? (((u64)flipf(dot) << 32) | (u32)(2047 - m)) : 0ull;
        }
        if (C > 64) {
            bool act = (64 + lane) < C;
            int m = act ? (int)s_cand[r][64 + lane] : 0;
            const float* kr = knb + (size_t)m * DH_;
            float dot = 0.f;
            #pragma unroll
            for (int d4 = 0; d4 < 16; ++d4) {
                float4 kx = *(const float4*)(kr + (d4 << 2));
                float4 qx = *(const float4*)&s_qrow[r][d4 << 2];
                dot += kx.x * qx.x + kx.y * qx.y + kx.z * qx.z + kx.w * qx.w;
            }
            keyB = act ? (((u64)flipf(dot) << 32) | (u32)(2047 - m)) : 0ull;
        }
        u64 v;
        if (C <= 64) {
            v = (lane < C) ? ~keyA : ~0ull;
            v = bsort64_asc(v, lane);
        } else {
            u64 a  = ~keyA;
            u64 bq = ~keyB;
            a  = bsort64_asc(a, lane);
            bq = bsort64_asc(bq, lane);
            u64 bb = __shfl(bq, 63 - lane);
            u64 s2 = (lane < 32) ? a : bb;   // bitonic: best-32(a) asc, best-32(b) desc
            #pragma unroll
            for (int j = 32; j >= 1; j >>= 1) {
                u64 ov = __shfl_xor(s2, j);
                bool keepMin = ((lane & j) == 0);
                bool less = s2 < ov;
                s2 = (keepMin == less) ? s2 : ov;
            }
            v = s2;
        }
        if (lane < 32) {
            u64 e = ~v;
            mycv = unflipf((u32)(e >> 32));
            myci = 2047 - (int)(u32)(e & 0xffffffffu);
        }
    }
    __syncthreads();   // #3: local/denom adds complete

    // ---- phase V: combine + exact retrieved + write ----
    {
        const int r = w;
        float lv = s_local[r][lane] / s_denom[r];
        float maxv = __shfl(mycv, 0);
        float pt = (lane < 32) ? __expf(SCALE_ * (mycv - maxv)) : 0.f;
        float rs = pt;
        #pragma unroll
        for (int off = 32; off; off >>= 1) rs += __shfl_xor(rs, off);
        float ret = 0.f;
        const float* knb2 = kn + (size_t)b * L_ * DH_ + lane;
        #pragma unroll 8
        for (int tt = 0; tt < 32; ++tt) {
            int   m  = __shfl(myci, tt);
            float pv = __shfl(pt, tt);
            ret += pv * knb2[(size_t)m * DH_];
        }
        attn[((size_t)(b * L_ + l0 + r)) * DM_ + h * DH_ + lane] = lv + ret / rs;
    }
}

// ---------------------------------------------------------------------------
extern "C" void kernel_launch(void* const* d_in, const int* in_sizes, int n_in,
                              void* d_out, int out_size, void* d_ws, size_t ws_size,
                              hipStream_t stream) {
    const float* q_in     = (const float*)d_in[0];
    const float* kv_in    = (const float*)d_in[1];
    const float* w_q      = (const float*)d_in[2];
    const float* w_kv     = (const float*)d_in[3];
    const float* w_concat = (const float*)d_in[4];
    float* out = (float*)d_out;

    float* ws   = (float*)d_ws;
    float* q    = ws;                    // 4,194,304 f
    float* attn = ws + 4194304;          // 4,194,304 f
    float* kv   = attn;                  // aliased: kv dead before attn written
    float* kn   = ws + 8388608;          // 262,144 f
    float* invn = ws + 8650752;          // 256 f
    __bf16* bfbase = (__bf16*)(ws + 8651008);
    __bf16* kh  = bfbase;                // 262,144 bf16
    __bf16* vT  = bfbase + 262144;       // 262,144 bf16  (b, 64, 2048)

    gemm128<<<dim3(DM_ / 128, (B_ * L_) / 128), 256, 0, stream>>>(q_in, w_q, q, DM_, DM_);
    gemm64<<<dim3(128 / 64, (B_ * L_) / 64), 256, 0, stream>>>(kv_in, w_kv, kv, 128, DM_);
    col_norms<<<B_ * 128, 256, 0, stream>>>(kv, invn);
    scale_kv<<<dim3(L_ / 64, B_), 256, 0, stream>>>(kv, invn, kn, kh, vT);
    attn_topk<<<dim3(L_ / 16, NH_, B_), 1024, 0, stream>>>(q, kn, kh, vT, attn);
    gemm128<<<dim3(DM_ / 128, (B_ * L_) / 128), 256, 0, stream>>>(attn, w_concat, out, DM_, DM_);
}

// Round 4
// 1041.079 us; speedup vs baseline: 1.0549x; 1.0549x over previous
//
#include <hip/hip_runtime.h>
#include <cstddef>
#include <cstring>

#define B_    2
#define L_    2048
#define DM_   1024
#define NH_   16
#define DH_   64
#define SCALE_ 0.125f   // 1/sqrt(64)

typedef __bf16 bf16x8 __attribute__((ext_vector_type(8)));
typedef float  f32x4  __attribute__((ext_vector_type(4)));
typedef unsigned short ushort8v __attribute__((ext_vector_type(8)));
typedef unsigned long long u64;
typedef unsigned int u32;

__device__ __forceinline__ u32 flipf(float f) {
    u32 u = __float_as_uint(f);
    return (u & 0x80000000u) ? ~u : (u | 0x80000000u);
}
__device__ __forceinline__ float unflipf(u32 k) {
    u32 u = (k & 0x80000000u) ? (k ^ 0x80000000u) : ~k;
    return __uint_as_float(u);
}
__device__ __forceinline__ float bf2f(unsigned short u) {
    return __uint_as_float(((u32)u) << 16);
}
__device__ __forceinline__ unsigned short f2bf(float f) {
    __bf16 h = (__bf16)f;
    unsigned short u;
    __builtin_memcpy(&u, &h, 2);
    return u;
}

// ---------------------------------------------------------------------------
// GEMM 128x128 tile, 8x8 microtile, fp32, C = A(MxK) @ W(KxN)
// (unchanged from round 1 — keeps q / out bit-identical across rounds)
// ---------------------------------------------------------------------------
__global__ __launch_bounds__(256)
void gemm128(const float* __restrict__ A, const float* __restrict__ W,
             float* __restrict__ C, int N, int K) {
    __shared__ float As[16][136];
    __shared__ float Ws[16][136];
    const int t  = threadIdx.x;
    const int bm = blockIdx.y << 7;
    const int bn = blockIdx.x << 7;
    const int tm = (t >> 4) << 3;
    const int tn = (t & 15) << 3;
    float acc[8][8] = {};
    const int am = t >> 1;
    const int ak = (t & 1) << 3;
    const int wk = t >> 4;
    const int wn = (t & 15) << 3;
    const float* Ap = A + (size_t)(bm + am) * K + ak;
    const float* Wp = W + (size_t)wk * N + bn + wn;
    for (int k0 = 0; k0 < K; k0 += 16) {
        float4 a0 = *(const float4*)(Ap + k0);
        float4 a1 = *(const float4*)(Ap + k0 + 4);
        float4 w0 = *(const float4*)(Wp + (size_t)k0 * N);
        float4 w1 = *(const float4*)(Wp + (size_t)k0 * N + 4);
        __syncthreads();
        As[ak+0][am] = a0.x; As[ak+1][am] = a0.y; As[ak+2][am] = a0.z; As[ak+3][am] = a0.w;
        As[ak+4][am] = a1.x; As[ak+5][am] = a1.y; As[ak+6][am] = a1.z; As[ak+7][am] = a1.w;
        *(float4*)&Ws[wk][wn]     = w0;
        *(float4*)&Ws[wk][wn + 4] = w1;
        __syncthreads();
        #pragma unroll
        for (int kk = 0; kk < 16; ++kk) {
            float a_[8], w_[8];
            *(float4*)&a_[0] = *(const float4*)&As[kk][tm];
            *(float4*)&a_[4] = *(const float4*)&As[kk][tm + 4];
            *(float4*)&w_[0] = *(const float4*)&Ws[kk][tn];
            *(float4*)&w_[4] = *(const float4*)&Ws[kk][tn + 4];
            #pragma unroll
            for (int i = 0; i < 8; ++i)
                #pragma unroll
                for (int j = 0; j < 8; ++j)
                    acc[i][j] += a_[i] * w_[j];
        }
    }
    #pragma unroll
    for (int i = 0; i < 8; ++i) {
        float* Cp = C + (size_t)(bm + tm + i) * N + bn + tn;
        float4 o0 = {acc[i][0], acc[i][1], acc[i][2], acc[i][3]};
        float4 o1 = {acc[i][4], acc[i][5], acc[i][6], acc[i][7]};
        *(float4*)Cp       = o0;
        *(float4*)(Cp + 4) = o1;
    }
}

// ---------------------------------------------------------------------------
// GEMM 64x64 tile, 4x4 microtile (skinny kv projection, N=128)
// ---------------------------------------------------------------------------
__global__ __launch_bounds__(256)
void gemm64(const float* __restrict__ A, const float* __restrict__ W,
            float* __restrict__ C, int N, int K) {
    __shared__ float As[16][68];
    __shared__ float Ws[16][68];
    const int t  = threadIdx.x;
    const int bm = blockIdx.y << 6;
    const int bn = blockIdx.x << 6;
    const int tm = (t >> 4) << 2;
    const int tn = (t & 15) << 2;
    float acc[4][4] = {};
    const int am = t >> 2;
    const int ak = (t & 3) << 2;
    const int wk = t >> 4;
    const int wn = (t & 15) << 2;
    const float* Ap = A + (size_t)(bm + am) * K + ak;
    const float* Wp = W + (size_t)wk * N + bn + wn;
    for (int k0 = 0; k0 < K; k0 += 16) {
        float4 av = *(const float4*)(Ap + k0);
        float4 wv = *(const float4*)(Wp + (size_t)k0 * N);
        __syncthreads();
        As[ak+0][am] = av.x; As[ak+1][am] = av.y; As[ak+2][am] = av.z; As[ak+3][am] = av.w;
        *(float4*)&Ws[wk][wn] = wv;
        __syncthreads();
        #pragma unroll
        for (int kk = 0; kk < 16; ++kk) {
            float a_[4], w_[4];
            *(float4*)&a_[0] = *(const float4*)&As[kk][tm];
            *(float4*)&w_[0] = *(const float4*)&Ws[kk][tn];
            #pragma unroll
            for (int i = 0; i < 4; ++i)
                #pragma unroll
                for (int j = 0; j < 4; ++j)
                    acc[i][j] += a_[i] * w_[j];
        }
    }
    #pragma unroll
    for (int i = 0; i < 4; ++i) {
        float4 o = {acc[i][0], acc[i][1], acc[i][2], acc[i][3]};
        *(float4*)(C + (size_t)(bm + tm + i) * N + bn + tn) = o;
    }
}

// ---------------------------------------------------------------------------
// Column (sequence-axis) L2 norms of kv -> inv_norm[b][c]
// ---------------------------------------------------------------------------
__global__ __launch_bounds__(256)
void col_norms(const float* __restrict__ kv, float* __restrict__ invn) {
    const int bc = blockIdx.x;
    const int b  = bc >> 7;
    const int c  = bc & 127;
    const int t  = threadIdx.x;
    const float* base = kv + (size_t)b * L_ * 128 + c;
    float ss = 0.f;
    for (int l = t; l < L_; l += 256) {
        float x = base[(size_t)l * 128];
        ss += x * x;
    }
    #pragma unroll
    for (int off = 32; off; off >>= 1) ss += __shfl_xor(ss, off);
    __shared__ float red[4];
    if ((t & 63) == 0) red[t >> 6] = ss;
    __syncthreads();
    if (t == 0) {
        float tot = red[0] + red[1] + red[2] + red[3];
        invn[bc] = 1.f / fmaxf(sqrtf(tot), 1e-12f);
    }
}

// ---------------------------------------------------------------------------
// Scale kv by inv-norms: kn fp32 (b,l,64), kh bf16 (b,l,64), vT bf16 (b,64,l)
// ---------------------------------------------------------------------------
__global__ __launch_bounds__(256)
void scale_kv(const float* __restrict__ kv, const float* __restrict__ invn,
              float* __restrict__ kn, __bf16* __restrict__ kh,
              __bf16* __restrict__ vT) {
    const int b  = blockIdx.y;
    const int l0 = blockIdx.x << 6;
    const int t  = threadIdx.x;
    __shared__ float s_inv[128];
    __shared__ float s_vt[64][65];
    if (t < 128) s_inv[t] = invn[b * 128 + t];
    __syncthreads();
    #pragma unroll
    for (int rep = 0; rep < 8; ++rep) {
        int idx = (rep << 8) + t;          // 0..2047
        int li  = idx >> 5;                // 0..63
        int c4  = (idx & 31) << 2;         // 0..124
        float4 x = *(const float4*)(kv + ((size_t)(b * L_ + l0 + li)) * 128 + c4);
        x.x *= s_inv[c4]; x.y *= s_inv[c4+1]; x.z *= s_inv[c4+2]; x.w *= s_inv[c4+3];
        if (c4 < 64) {
            size_t o = ((size_t)(b * L_ + l0 + li)) * DH_ + c4;
            *(float4*)(kn + o) = x;
            kh[o+0] = (__bf16)x.x; kh[o+1] = (__bf16)x.y;
            kh[o+2] = (__bf16)x.z; kh[o+3] = (__bf16)x.w;
        } else {
            int d = c4 - 64;
            s_vt[d+0][li] = x.x; s_vt[d+1][li] = x.y; s_vt[d+2][li] = x.z; s_vt[d+3][li] = x.w;
        }
    }
    __syncthreads();
    #pragma unroll
    for (int rep = 0; rep < 4; ++rep) {
        int idx = (rep << 8) + t;          // 0..1023
        int d   = idx >> 4;                // 0..63
        int j   = (idx & 15) << 2;         // 0..60
        size_t o = ((size_t)b * DH_ + d) * L_ + l0 + j;
        vT[o+0] = (__bf16)s_vt[d][j+0];
        vT[o+1] = (__bf16)s_vt[d][j+1];
        vT[o+2] = (__bf16)s_vt[d][j+2];
        vT[o+3] = (__bf16)s_vt[d][j+3];
    }
}

// ---------------------------------------------------------------------------
// Fused attention + exact top-32.  Block: 1024 thr (16 waves) = (b,h,16 rows).
// Shuffle-free top-k: ballot radix-select (no bitonic sorts, no bpermute
// chains).  No softmax max-subtraction (|s*scale| <= ~0.1 -> exp safe),
// which removes one barrier and lets T/F/L1 phases run desynchronized.
// LDS 78.8 KB -> 2 blocks/CU.
// ---------------------------------------------------------------------------
#define SSTRIDE_ 2072   // ushort row stride: S-writes 4-way max, L1 reads 2-way

__global__ __launch_bounds__(1024, 8)
void attn_topk(const float* __restrict__ q,    // (B, L, 1024) fp32
               const float* __restrict__ kn,   // (B, L, 64)  fp32
               const __bf16* __restrict__ kh,  // (B, L, 64)  bf16
               const __bf16* __restrict__ vT,  // (B, 64, L)  bf16
               float* __restrict__ attn) {     // (B, L, 1024)
    const int l0   = blockIdx.x << 4;
    const int h    = blockIdx.y;
    const int b    = blockIdx.z;
    const int t    = threadIdx.x;
    const int w    = t >> 6;          // wave 0..15
    const int lane = t & 63;
    const int quad = lane >> 4;
    const int n15  = lane & 15;

    __shared__ unsigned short s_sims[16 * SSTRIDE_];        // 66,304 B
    __shared__ unsigned short s_cand[16][128];              //  4,096 B
    __shared__ __align__(16) u64 s_sel[16][32];             //  8,192 B
    __shared__ float s_denom[16];
    __shared__ float s_local[16][66];                       //  4,224 B
    // total ~78.8 KB -> 2 blocks/CU

    // ---- init accumulators ----
    {
        float* sl = &s_local[0][0];
        for (int i = t; i < 16 * 66; i += 1024) sl[i] = 0.f;
        if (t < 16) s_denom[t] = 0.f;
    }

    // ---- phase S: sims via bf16 MFMA (wave w -> m in [128w,128w+128)) ----
    {
        bf16x8 qf[2];
        const float* qp = q + ((size_t)(b * L_ + l0 + n15)) * DM_ + h * DH_ + (quad << 3);
        #pragma unroll
        for (int ks = 0; ks < 2; ++ks) {
            float4 x0 = *(const float4*)(qp + (ks << 5));
            float4 x1 = *(const float4*)(qp + (ks << 5) + 4);
            float xv[8] = {x0.x, x0.y, x0.z, x0.w, x1.x, x1.y, x1.z, x1.w};
            #pragma unroll
            for (int i2 = 0; i2 < 8; ++i2) qf[ks][i2] = (__bf16)xv[i2];
        }
        const __bf16* khb = kh + (size_t)b * L_ * DH_;
        #pragma unroll 2
        for (int j = 0; j < 8; ++j) {
            int m0 = (w << 7) + (j << 4);
            const __bf16* kp = khb + (size_t)(m0 + n15) * DH_ + (quad << 3);
            bf16x8 k0 = *(const bf16x8*)(kp);
            bf16x8 k1 = *(const bf16x8*)(kp + 32);
            f32x4 acc = {0.f, 0.f, 0.f, 0.f};
            acc = __builtin_amdgcn_mfma_f32_16x16x32_bf16(qf[0], k0, acc, 0, 0, 0);
            acc = __builtin_amdgcn_mfma_f32_16x16x32_bf16(qf[1], k1, acc, 0, 0, 0);
            #pragma unroll
            for (int rr = 0; rr < 4; ++rr)
                s_sims[((quad << 2) + rr) * SSTRIDE_ + m0 + n15] = f2bf(acc[rr]);
        }
    }
    __syncthreads();   // #1: sims + zeros visible

    // ---- phase T: threshold scan + candidate compaction (wave w = row w) ----
    int C;
    {
        const int r = w;
        const unsigned short* srow = s_sims + r * SSTRIDE_;
        ushort8v rv[4];
        #pragma unroll
        for (int j = 0; j < 4; ++j)
            rv[j] = *(const ushort8v*)(srow + (j << 9) + (lane << 3));
        float bv = -3e38f;
        #pragma unroll
        for (int j = 0; j < 4; ++j)
            #pragma unroll
            for (int e = 0; e < 8; ++e) bv = fmaxf(bv, bf2f(rv[j][e]));
        // radix-select: 32nd-largest lane-max via ballot (no LDS, no shuffles)
        u32 key = flipf(bv);
        u32 thr = 0;
        #pragma unroll
        for (int bp = 31; bp >= 0; --bp) {
            u32 tt = thr | (1u << bp);
            if (__popcll(__ballot(key >= tt)) >= 32) thr = tt;
        }
        float thrv = unflipf(thr) - 0.01f;   // margin covers bf16 sims error
        // ballot-compact candidate indices (from registers)
        int base = 0;
        #pragma unroll
        for (int j = 0; j < 4; ++j) {
            #pragma unroll
            for (int e = 0; e < 8; ++e) {
                bool pred = bf2f(rv[j][e]) >= thrv;
                u64 mk = __ballot(pred);
                if (pred) {
                    int pos = base + __popcll(mk & ((1ull << lane) - 1));
                    if (pos < 128)
                        s_cand[r][pos] = (unsigned short)((j << 9) + (lane << 3) + e);
                }
                base += __popcll(mk);
            }
        }
        C = base < 128 ? base : 128;
    }

    // ---- phase L1: local = exp(s*scale) @ v, bf16 MFMA, no max-subtract ----
    {
        f32x4 accL[4] = {{0,0,0,0},{0,0,0,0},{0,0,0,0},{0,0,0,0}};
        float psum = 0.f;
        const __bf16* vtb = vT + (size_t)b * DH_ * L_;
        #pragma unroll
        for (int ks = 0; ks < 4; ++ks) {
            int mb = (w << 7) + (ks << 5);
            ushort8v pu = *(const ushort8v*)(s_sims + n15 * SSTRIDE_ + mb + (quad << 3));
            bf16x8 af;
            #pragma unroll
            for (int e = 0; e < 8; ++e) {
                float p = __expf(SCALE_ * bf2f(pu[e]));
                psum += p;
                af[e] = (__bf16)p;
            }
            #pragma unroll
            for (int nn = 0; nn < 4; ++nn) {
                bf16x8 bv8 = *(const bf16x8*)(vtb + (size_t)((nn << 4) + n15) * L_ + mb + (quad << 3));
                accL[nn] = __builtin_amdgcn_mfma_f32_16x16x32_bf16(af, bv8, accL[nn], 0, 0, 0);
            }
        }
        psum += __shfl_xor(psum, 16);
        psum += __shfl_xor(psum, 32);
        if (lane < 16) atomicAdd(&s_denom[lane], psum);
        #pragma unroll
        for (int nn = 0; nn < 4; ++nn)
            #pragma unroll
            for (int rr = 0; rr < 4; ++rr)
                atomicAdd(&s_local[(quad << 2) + rr][(nn << 4) + n15], accL[nn][rr]);
    }

    // ---- phase F: exact fp32 refine + ballot radix top-32 (wave w = row w) ----
    {
        const int r = w;
        const float* knb = kn + (size_t)b * L_ * DH_;
        const float* qr  = q + ((size_t)(b * L_ + l0 + r)) * DM_ + h * DH_;  // uniform -> s_load
        int mA = (lane < C) ? (int)s_cand[r][lane] : 0;
        float dotA = 0.f;
        {
            const float* kr = knb + (size_t)mA * DH_;
            #pragma unroll
            for (int d4 = 0; d4 < 16; ++d4) {
                float4 kx = *(const float4*)(kr + (d4 << 2));
                float4 qx = *(const float4*)(qr + (d4 << 2));
                dotA += kx.x * qx.x + kx.y * qx.y + kx.z * qx.z + kx.w * qx.w;
            }
        }
        u32 keyA = (lane < C) ? flipf(dotA) : 0u;
        if (C <= 64) {
            u32 thr2 = 0;
            #pragma unroll
            for (int bp = 31; bp >= 0; --bp) {
                u32 tt = thr2 | (1u << bp);
                if (__popcll(__ballot(keyA >= tt)) >= 32) thr2 = tt;
            }
            bool pred = keyA >= thr2;
            u64 mk = __ballot(pred);
            float pt = __expf(SCALE_ * dotA);
            if (pred) {
                int pos = __popcll(mk & ((1ull << lane) - 1));
                if (pos < 32)
                    s_sel[r][pos] = ((u64)__float_as_uint(pt) << 32) | (u32)mA;
            }
        } else {
            int mB = (64 + lane < C) ? (int)s_cand[r][64 + lane] : 0;
            float dotB = 0.f;
            {
                const float* kr = knb + (size_t)mB * DH_;
                #pragma unroll
                for (int d4 = 0; d4 < 16; ++d4) {
                    float4 kx = *(const float4*)(kr + (d4 << 2));
                    float4 qx = *(const float4*)(qr + (d4 << 2));
                    dotB += kx.x * qx.x + kx.y * qx.y + kx.z * qx.z + kx.w * qx.w;
                }
            }
            u32 keyB = (64 + lane < C) ? flipf(dotB) : 0u;
            u32 thr2 = 0;
            #pragma unroll
            for (int bp = 31; bp >= 0; --bp) {
                u32 tt = thr2 | (1u << bp);
                int c2 = __popcll(__ballot(keyA >= tt)) + __popcll(__ballot(keyB >= tt));
                if (c2 >= 32) thr2 = tt;
            }
            bool pA = keyA >= thr2, pB = keyB >= thr2;
            u64 mkA = __ballot(pA);
            u64 mkB = __ballot(pB);
            int cA = __popcll(mkA);
            float ptA = __expf(SCALE_ * dotA);
            float ptB = __expf(SCALE_ * dotB);
            if (pA) {
                int pos = __popcll(mkA & ((1ull << lane) - 1));
                if (pos < 32)
                    s_sel[r][pos] = ((u64)__float_as_uint(ptA) << 32) | (u32)mA;
            }
            if (pB) {
                int pos = cA + __popcll(mkB & ((1ull << lane) - 1));
                if (pos < 32)
                    s_sel[r][pos] = ((u64)__float_as_uint(ptB) << 32) | (u32)mB;
            }
        }
    }
    __syncthreads();   // #2: local/denom atomics complete

    // ---- phase V: combine + exact retrieved + write (wave w = row w) ----
    {
        const int r = w;
        float lv = s_local[r][lane] / s_denom[r];
        float rs = 0.f, ret = 0.f;
        const float* knb2 = kn + (size_t)b * L_ * DH_ + lane;
        #pragma unroll 4
        for (int i = 0; i < 16; ++i) {
            u64 s0 = s_sel[r][2 * i];        // broadcast LDS reads
            u64 s1 = s_sel[r][2 * i + 1];
            float p0 = __uint_as_float((u32)(s0 >> 32));
            float p1 = __uint_as_float((u32)(s1 >> 32));
            int   m0 = (int)(u32)(s0 & 0xffffffffu);
            int   m1 = (int)(u32)(s1 & 0xffffffffu);
            rs  += p0 + p1;
            ret += p0 * knb2[(size_t)m0 * DH_] + p1 * knb2[(size_t)m1 * DH_];
        }
        attn[((size_t)(b * L_ + l0 + r)) * DM_ + h * DH_ + lane] = lv + ret / rs;
    }
}

// ---------------------------------------------------------------------------
extern "C" void kernel_launch(void* const* d_in, const int* in_sizes, int n_in,
                              void* d_out, int out_size, void* d_ws, size_t ws_size,
                              hipStream_t stream) {
    const float* q_in     = (const float*)d_in[0];
    const float* kv_in    = (const float*)d_in[1];
    const float* w_q      = (const float*)d_in[2];
    const float* w_kv     = (const float*)d_in[3];
    const float* w_concat = (const float*)d_in[4];
    float* out = (float*)d_out;

    float* ws   = (float*)d_ws;
    float* q    = ws;                    // 4,194,304 f
    float* attn = ws + 4194304;          // 4,194,304 f
    float* kv   = attn;                  // aliased: kv dead before attn written
    float* kn   = ws + 8388608;          // 262,144 f
    float* invn = ws + 8650752;          // 256 f
    __bf16* bfbase = (__bf16*)(ws + 8651008);
    __bf16* kh  = bfbase;                // 262,144 bf16
    __bf16* vT  = bfbase + 262144;       // 262,144 bf16  (b, 64, 2048)

    gemm128<<<dim3(DM_ / 128, (B_ * L_) / 128), 256, 0, stream>>>(q_in, w_q, q, DM_, DM_);
    gemm64<<<dim3(128 / 64, (B_ * L_) / 64), 256, 0, stream>>>(kv_in, w_kv, kv, 128, DM_);
    col_norms<<<B_ * 128, 256, 0, stream>>>(kv, invn);
    scale_kv<<<dim3(L_ / 64, B_), 256, 0, stream>>>(kv, invn, kn, kh, vT);
    attn_topk<<<dim3(L_ / 16, NH_, B_), 1024, 0, stream>>>(q, kn, kh, vT, attn);
    gemm128<<<dim3(DM_ / 128, (B_ * L_) / 128), 256, 0, stream>>>(attn, w_concat, out, DM_, DM_);
}